// Round 5
// baseline (1509.554 us; speedup 1.0000x reference)
//
#include <hip/hip_runtime.h>
#include <hip/hip_bf16.h>

#define FDIM 64
#define LFP 128
#define RROUNDS 4
#define BM 64      // nodes per block in round kernel
#define SCAN_B 1024

typedef __attribute__((ext_vector_type(8))) short bf16x8;
typedef __attribute__((ext_vector_type(4))) float f32x4;

__device__ __forceinline__ float bf2f(unsigned short u) {
    unsigned int x = ((unsigned int)u) << 16;
    float f;
    __builtin_memcpy(&f, &x, 4);
    return f;
}
__device__ __forceinline__ unsigned short f2bf(float x) {
    unsigned int u;
    __builtin_memcpy(&u, &x, 4);
    unsigned int r = (u + 0x7fffu + ((u >> 16) & 1u)) >> 16;  // RNE
    return (unsigned short)r;
}

// ---------------- CSR build ----------------
__global__ void hist_kernel(const int* __restrict__ dst, int* __restrict__ cnt, int nE) {
    int e = blockIdx.x * blockDim.x + threadIdx.x;
    if (e < nE) atomicAdd(&cnt[dst[e]], 1);
}

__global__ __launch_bounds__(256) void scan1_kernel(const int* __restrict__ cnt,
                                                    int* __restrict__ rp, int* __restrict__ bsum, int n) {
    __shared__ int s[256];
    int t = threadIdx.x;
    int base = blockIdx.x * SCAN_B;
    int v[4], sum = 0;
#pragma unroll
    for (int i = 0; i < 4; i++) {
        int idx = base + t * 4 + i;
        v[i] = (idx < n) ? cnt[idx] : 0;
        sum += v[i];
    }
    s[t] = sum;
    __syncthreads();
    for (int d = 1; d < 256; d <<= 1) {
        int x = (t >= d) ? s[t - d] : 0;
        __syncthreads();
        s[t] += x;
        __syncthreads();
    }
    int excl = (t > 0) ? s[t - 1] : 0;
#pragma unroll
    for (int i = 0; i < 4; i++) {
        int idx = base + t * 4 + i;
        if (idx < n) { rp[idx] = excl; excl += v[i]; }
    }
    if (t == 255) bsum[blockIdx.x] = s[255];
}

// wave-parallel exclusive scan of block sums (nb <= 64 fast path)
__global__ void scan2_kernel(int* __restrict__ bsum, int nb) {
    int t = threadIdx.x;
    if (nb <= 64) {
        int v = (t < nb) ? bsum[t] : 0;
#pragma unroll
        for (int d = 1; d < 64; d <<= 1) {
            int x = __shfl_up(v, d);
            if (t >= d) v += x;
        }
        int e = __shfl_up(v, 1);
        if (t == 0) e = 0;
        if (t < nb) bsum[t] = e;
    } else if (t == 0) {
        int acc = 0;
        for (int i = 0; i < nb; i++) { int x = bsum[i]; bsum[i] = acc; acc += x; }
    }
}

__global__ void scan3_kernel(int* __restrict__ rp, const int* __restrict__ bsum,
                             int* __restrict__ cursor, int n, int nE) {
    int idx = blockIdx.x * blockDim.x + threadIdx.x;
    if (idx < n) {
        int v = rp[idx] + bsum[idx / SCAN_B];
        rp[idx] = v;
        cursor[idx] = v;
    }
    if (idx == n) rp[n] = nE;
}

// csr2[p] = (src, dst) sorted by dst
__global__ void fill_kernel(const int* __restrict__ src, const int* __restrict__ dst,
                            int* __restrict__ cursor, int2* __restrict__ csr2, int nE) {
    int e = blockIdx.x * blockDim.x + threadIdx.x;
    if (e < nE) {
        int d = dst[e];
        int p = atomicAdd(&cursor[d], 1);
        csr2[p] = make_int2(src[e], d);
    }
}

// ---------------- pipeline ----------------
__global__ void prep_kernel(const float* __restrict__ Wh, const float* __restrict__ Wfp,
                            unsigned short* __restrict__ whT, unsigned short* __restrict__ wfpT) {
    int o = blockIdx.x * blockDim.x + threadIdx.x;
    if (o < RROUNDS * FDIM * FDIM) {
        int r = o >> 12, rem = o & 4095, j = rem >> 6, k = rem & 63;
        whT[o] = f2bf(Wh[r * 4096 + k * 64 + j]);
    } else {
        int o2 = o - RROUNDS * FDIM * FDIM;
        int r = o2 >> 13, rem = o2 & 8191, l = rem >> 6, k = rem & 63;
        wfpT[o2] = f2bf(Wfp[r * 8192 + k * 128 + l]);
    }
}

__global__ void init_kernel(const int* __restrict__ feat, const float* __restrict__ table,
                            unsigned short* __restrict__ emb, float* __restrict__ f, int n) {
    int gid = blockIdx.x * blockDim.x + threadIdx.x;
    if (gid < n * FDIM) {
        int node = gid >> 6;
        int d = gid & 63;
        emb[gid] = f2bf(table[feat[node] * FDIM + d]);
    }
    if (gid < LFP) f[gid] = 0.f;
}

// Fused round v2: edge-parallel gather (LDS fp32 ds_add_f32) -> MFMA MLP.
// Block owns 64 dst rows = contiguous CSR slice [rp[base], rp[base+64]).
// 32 groups x 8 lanes; all edge iterations independent -> deep MLP, no chains.
// LDS union: fp32 accumulator (16.9KB) reused as sWfp tile (18.4KB) after barrier.
__global__ __launch_bounds__(256) void round_kernel(
        const unsigned short* __restrict__ embIn, unsigned short* __restrict__ embOut,
        const int* __restrict__ rp, const int2* __restrict__ csr2,
        const unsigned short* __restrict__ whT, const unsigned short* __restrict__ wfpT,
        const float* __restrict__ bh, const float* __restrict__ bfp,
        float* __restrict__ f, int N) {
    __shared__ __align__(16) unsigned short sU[128 * 72];  // union: sVf fp32 | sWfp bf16
    __shared__ unsigned short sV[BM * 72];
    __shared__ unsigned short sWh[64 * 72];
    __shared__ float sBh[64];
    __shared__ float sBfp[128];
    __shared__ float sF[128];

    float* sVf = (float*)sU;  // [64][66] fp32 accumulator (16896 B <= 18432 B)

    int tid = threadIdx.x;
    int base = blockIdx.x * BM;
    int lane = tid & 63, w = tid >> 6;

    if (tid < 128) { sF[tid] = 0.f; sBfp[tid] = bfp[tid]; }
    if (tid < 64) sBh[tid] = bh[tid];
    for (int i = tid; i < 64 * 66; i += 256) sVf[i] = 0.f;
#pragma unroll
    for (int it = 0; it < 2; ++it) {  // WhT: 4096 bf16
        int idx = it * 2048 + tid * 8;
        *reinterpret_cast<bf16x8*>(sWh + (idx >> 6) * 72 + (idx & 63)) =
            *reinterpret_cast<const bf16x8*>(whT + idx);
    }
    __syncthreads();

    // ---- edge-parallel gather ----
    {
        int grp = tid >> 3;  // 0..31
        int q = tid & 7;     // 16B chunk of the 128B emb row
        int nHi = base + BM; if (nHi > N) nHi = N;
        int pStart = rp[base], pEnd = rp[nHi];
#pragma unroll 4
        for (int p = pStart + grp; p < pEnd; p += 32) {
            int2 e = csr2[p];  // (src, dst) — 8 lanes broadcast
            bf16x8 u = *reinterpret_cast<const bf16x8*>(embIn + (size_t)e.x * 64 + q * 8);
            float* dr = sVf + (e.y - base) * 66 + q * 8;
#pragma unroll
            for (int x = 0; x < 8; ++x) atomicAdd(dr + x, bf2f((unsigned short)u[x]));
        }
    }
    __syncthreads();

    // ---- convert + self: v = accum + emb[self], thread t -> row t>>2, 16 cols ----
    {
        int row = tid >> 2, seg = tid & 3;
        int n = base + row;
        bf16x8 o0, o1;
        if (n < N) {
            const unsigned short* sp = embIn + (size_t)n * 64 + seg * 16;
            bf16x8 s0 = *reinterpret_cast<const bf16x8*>(sp);
            bf16x8 s1 = *reinterpret_cast<const bf16x8*>(sp + 8);
            const float* ap = sVf + row * 66 + seg * 16;
#pragma unroll
            for (int x = 0; x < 8; ++x) o0[x] = (short)f2bf(ap[x] + bf2f((unsigned short)s0[x]));
#pragma unroll
            for (int x = 0; x < 8; ++x) o1[x] = (short)f2bf(ap[8 + x] + bf2f((unsigned short)s1[x]));
        } else {
#pragma unroll
            for (int x = 0; x < 8; ++x) { o0[x] = 0; o1[x] = 0; }
        }
        *reinterpret_cast<bf16x8*>(sV + row * 72 + seg * 16) = o0;
        *reinterpret_cast<bf16x8*>(sV + row * 72 + seg * 16 + 8) = o1;
    }
    __syncthreads();  // all sVf reads done; union region free

    // ---- stage WfpT into union region (overlaps GEMM1 latency) ----
    unsigned short* sWfp = sU;
#pragma unroll
    for (int it = 0; it < 4; ++it) {  // 8192 bf16
        int idx = it * 2048 + tid * 8;
        *reinterpret_cast<bf16x8*>(sWfp + (idx >> 6) * 72 + (idx & 63)) =
            *reinterpret_cast<const bf16x8*>(wfpT + idx);
    }

    int m16 = lane & 15, g = lane >> 4;
    int arow = w * 16 + m16;

    // ---- GEMM1: r = relu(V @ Wh + bh) ----
    bf16x8 a0 = *reinterpret_cast<const bf16x8*>(sV + arow * 72 + g * 8);
    bf16x8 a1 = *reinterpret_cast<const bf16x8*>(sV + arow * 72 + 32 + g * 8);
    f32x4 acc1[4];
#pragma unroll
    for (int c = 0; c < 4; ++c) {
        bf16x8 b0 = *reinterpret_cast<const bf16x8*>(sWh + (c * 16 + m16) * 72 + g * 8);
        bf16x8 b1 = *reinterpret_cast<const bf16x8*>(sWh + (c * 16 + m16) * 72 + 32 + g * 8);
        f32x4 z = {0.f, 0.f, 0.f, 0.f};
        z = __builtin_amdgcn_mfma_f32_16x16x32_bf16(a0, b0, z, 0, 0, 0);
        z = __builtin_amdgcn_mfma_f32_16x16x32_bf16(a1, b1, z, 0, 0, 0);
        acc1[c] = z;
    }
    // bias+relu; write r into own wave strip (in-wave ordered via data dep; no cross-wave readers)
    // C layout: row=(lane>>4)*4+reg, col=c*16+(lane&15)
#pragma unroll
    for (int c = 0; c < 4; ++c) {
        float bias = sBh[c * 16 + m16];
#pragma unroll
        for (int reg = 0; reg < 4; ++reg) {
            float rv = fmaxf(acc1[c][reg] + bias, 0.f);
            sV[(w * 16 + g * 4 + reg) * 72 + c * 16 + m16] = f2bf(rv);
        }
    }
    __syncthreads();  // r-writes + sWfp staging complete

    // store r -> embOut (next round input)
#pragma unroll
    for (int it = 0; it < 2; ++it) {
        int idx = it * 2048 + tid * 8;
        int nl = idx >> 6;
        if (base + nl < N)
            *reinterpret_cast<bf16x8*>(embOut + (size_t)base * 64 + idx) =
                *reinterpret_cast<const bf16x8*>(sV + nl * 72 + (idx & 63));
    }

    // ---- GEMM2: z = r @ Wfp + bfp  (16 x 128 per wave) ----
    bf16x8 ra0 = *reinterpret_cast<const bf16x8*>(sV + arow * 72 + g * 8);
    bf16x8 ra1 = *reinterpret_cast<const bf16x8*>(sV + arow * 72 + 32 + g * 8);
    f32x4 z[8];
#pragma unroll
    for (int t = 0; t < 8; ++t) {
        bf16x8 b0 = *reinterpret_cast<const bf16x8*>(sWfp + (t * 16 + m16) * 72 + g * 8);
        bf16x8 b1 = *reinterpret_cast<const bf16x8*>(sWfp + (t * 16 + m16) * 72 + 32 + g * 8);
        f32x4 zz = {0.f, 0.f, 0.f, 0.f};
        zz = __builtin_amdgcn_mfma_f32_16x16x32_bf16(ra0, b0, zz, 0, 0, 0);
        zz = __builtin_amdgcn_mfma_f32_16x16x32_bf16(ra1, b1, zz, 0, 0, 0);
        float bias = sBfp[t * 16 + m16];
#pragma unroll
        for (int reg = 0; reg < 4; ++reg) zz[reg] += bias;
        z[t] = zz;
    }

    // ---- softmax over 128 cols per node-row (rows live in 16-lane groups) ----
#pragma unroll
    for (int reg = 0; reg < 4; ++reg) {
        float mx = -1e30f;
#pragma unroll
        for (int t = 0; t < 8; ++t) mx = fmaxf(mx, z[t][reg]);
#pragma unroll
        for (int d = 1; d < 16; d <<= 1) mx = fmaxf(mx, __shfl_xor(mx, d));
        float s = 0.f;
#pragma unroll
        for (int t = 0; t < 8; ++t) {
            float p = __expf(z[t][reg] - mx);
            z[t][reg] = p;
            s += p;
        }
#pragma unroll
        for (int d = 1; d < 16; d <<= 1) s += __shfl_xor(s, d);
        int node = base + w * 16 + g * 4 + reg;
        float inv = (node < N) ? (1.f / s) : 0.f;
#pragma unroll
        for (int t = 0; t < 8; ++t) z[t][reg] *= inv;
    }
#pragma unroll
    for (int t = 0; t < 8; ++t) {
        float v = z[t][0] + z[t][1] + z[t][2] + z[t][3];
        v += __shfl_xor(v, 16);
        v += __shfl_xor(v, 32);
        if (g == 0) atomicAdd(&sF[t * 16 + m16], v);
    }
    __syncthreads();
    if (tid < 128) unsafeAtomicAdd(&f[tid], sF[tid]);
}

__global__ void final_kernel(const float* __restrict__ f, const float* __restrict__ Wcl,
                             const float* __restrict__ bcl, float* __restrict__ out) {
    __shared__ float logits[10];
    int c = threadIdx.x;
    if (c < 10) {
        float acc = bcl[c];
        for (int l = 0; l < LFP; l++) acc = fmaf(f[l], Wcl[l * 10 + c], acc);
        logits[c] = acc;
    }
    __syncthreads();
    if (c == 0) {
        float m = -1e30f;
        for (int i = 0; i < 10; i++) m = fmaxf(m, logits[i]);
        float e[10], s = 0.f;
        for (int i = 0; i < 10; i++) { e[i] = __expf(logits[i] - m); s += e[i]; }
        for (int i = 0; i < 10; i++) out[i] = e[i] / s;
    }
}

extern "C" void kernel_launch(void* const* d_in, const int* in_sizes, int n_in,
                              void* d_out, int out_size, void* d_ws, size_t ws_size,
                              hipStream_t stream) {
    const int* feat = (const int*)d_in[0];
    const int* esrc = (const int*)d_in[1];
    const int* edst = (const int*)d_in[2];
    const float* table = (const float*)d_in[3];
    const float* Wh = (const float*)d_in[4];
    const float* bh = (const float*)d_in[5];
    const float* Wfp = (const float*)d_in[6];
    const float* bfp = (const float*)d_in[7];
    const float* Wcl = (const float*)d_in[8];
    const float* bcl = (const float*)d_in[9];
    float* out = (float*)d_out;
    int N = in_sizes[0];
    int nE = in_sizes[1];

    char* ws = (char*)d_ws;
    size_t off = 0;
    auto alloc = [&](size_t bytes) { void* p = ws + off; off += (bytes + 63) & ~(size_t)63; return p; };
    unsigned short* embA = (unsigned short*)alloc((size_t)N * 64 * 2);
    unsigned short* embB = (unsigned short*)alloc((size_t)N * 64 * 2);
    float* f           = (float*)alloc(LFP * 4);
    unsigned short* whT  = (unsigned short*)alloc(RROUNDS * 64 * 64 * 2);
    unsigned short* wfpT = (unsigned short*)alloc(RROUNDS * 128 * 64 * 2);
    int* cnt    = (int*)alloc((size_t)N * 4);
    int* rp     = (int*)alloc(((size_t)N + 1) * 4);
    int* cursor = (int*)alloc((size_t)N * 4);
    int* bsum   = (int*)alloc(((size_t)(N + SCAN_B - 1) / SCAN_B) * 4);
    int2* csr2  = (int2*)alloc((size_t)nE * 8);

    int nblk_scan = (N + SCAN_B - 1) / SCAN_B;

    // CSR build (rebuilt every call — deterministic, no cross-call state)
    hipMemsetAsync(cnt, 0, (size_t)N * 4, stream);
    hist_kernel<<<(nE + 255) / 256, 256, 0, stream>>>(edst, cnt, nE);
    scan1_kernel<<<nblk_scan, 256, 0, stream>>>(cnt, rp, bsum, N);
    scan2_kernel<<<1, 64, 0, stream>>>(bsum, nblk_scan);
    scan3_kernel<<<(N + 256) / 256, 256, 0, stream>>>(rp, bsum, cursor, N, nE);
    fill_kernel<<<(nE + 255) / 256, 256, 0, stream>>>(esrc, edst, cursor, csr2, nE);

    prep_kernel<<<192, 256, 0, stream>>>(Wh, Wfp, whT, wfpT);
    init_kernel<<<(N * FDIM + 255) / 256, 256, 0, stream>>>(feat, table, embA, f, N);

    unsigned short* eIn = embA;
    unsigned short* eOut = embB;
    for (int r = 0; r < RROUNDS; ++r) {
        round_kernel<<<(N + BM - 1) / BM, 256, 0, stream>>>(
            eIn, eOut, rp, csr2, whT + (size_t)r * 4096, wfpT + (size_t)r * 8192,
            bh + (size_t)r * FDIM, bfp + (size_t)r * LFP, f, N);
        unsigned short* t = eIn; eIn = eOut; eOut = t;
    }

    final_kernel<<<1, 64, 0, stream>>>(f, Wcl, bcl, out);
}

// Round 6
// 321.874 us; speedup vs baseline: 4.6899x; 4.6899x over previous
//
#include <hip/hip_runtime.h>
#include <hip/hip_bf16.h>

#define FDIM 64
#define LFP 128
#define RROUNDS 4
#define BM 64      // nodes per block in mlp kernel
#define SCAN_B 1024

typedef __attribute__((ext_vector_type(8))) short bf16x8;
typedef __attribute__((ext_vector_type(4))) float f32x4;

__device__ __forceinline__ float bf2f(unsigned short u) {
    unsigned int x = ((unsigned int)u) << 16;
    float f;
    __builtin_memcpy(&f, &x, 4);
    return f;
}
__device__ __forceinline__ unsigned short f2bf(float x) {
    unsigned int u;
    __builtin_memcpy(&u, &x, 4);
    unsigned int r = (u + 0x7fffu + ((u >> 16) & 1u)) >> 16;  // RNE
    return (unsigned short)r;
}

// ---------------- CSR build ----------------
__global__ void hist_kernel(const int* __restrict__ dst, int* __restrict__ cnt, int nE) {
    int e = blockIdx.x * blockDim.x + threadIdx.x;
    if (e < nE) atomicAdd(&cnt[dst[e]], 1);
}

__global__ __launch_bounds__(256) void scan1_kernel(const int* __restrict__ cnt,
                                                    int* __restrict__ rp, int* __restrict__ bsum, int n) {
    __shared__ int s[256];
    int t = threadIdx.x;
    int base = blockIdx.x * SCAN_B;
    int v[4], sum = 0;
#pragma unroll
    for (int i = 0; i < 4; i++) {
        int idx = base + t * 4 + i;
        v[i] = (idx < n) ? cnt[idx] : 0;
        sum += v[i];
    }
    s[t] = sum;
    __syncthreads();
    for (int d = 1; d < 256; d <<= 1) {
        int x = (t >= d) ? s[t - d] : 0;
        __syncthreads();
        s[t] += x;
        __syncthreads();
    }
    int excl = (t > 0) ? s[t - 1] : 0;
#pragma unroll
    for (int i = 0; i < 4; i++) {
        int idx = base + t * 4 + i;
        if (idx < n) { rp[idx] = excl; excl += v[i]; }
    }
    if (t == 255) bsum[blockIdx.x] = s[255];
}

// wave-parallel exclusive scan of block sums (nb <= 64 fast path)
__global__ void scan2_kernel(int* __restrict__ bsum, int nb) {
    int t = threadIdx.x;
    if (nb <= 64) {
        int v = (t < nb) ? bsum[t] : 0;
#pragma unroll
        for (int d = 1; d < 64; d <<= 1) {
            int x = __shfl_up(v, d);
            if (t >= d) v += x;
        }
        int e = __shfl_up(v, 1);
        if (t == 0) e = 0;
        if (t < nb) bsum[t] = e;
    } else if (t == 0) {
        int acc = 0;
        for (int i = 0; i < nb; i++) { int x = bsum[i]; bsum[i] = acc; acc += x; }
    }
}

__global__ void scan3_kernel(int* __restrict__ rp, const int* __restrict__ bsum,
                             int* __restrict__ cursor, int n, int nE) {
    int idx = blockIdx.x * blockDim.x + threadIdx.x;
    if (idx < n) {
        int v = rp[idx] + bsum[idx / SCAN_B];
        rp[idx] = v;
        cursor[idx] = v;
    }
    if (idx == n) rp[n] = nE;
}

__global__ void fill_kernel(const int* __restrict__ src, const int* __restrict__ dst,
                            int* __restrict__ cursor, int* __restrict__ csr, int nE) {
    int e = blockIdx.x * blockDim.x + threadIdx.x;
    if (e < nE) {
        int p = atomicAdd(&cursor[dst[e]], 1);
        csr[p] = src[e];
    }
}

// ---------------- pipeline ----------------
__global__ void prep_kernel(const float* __restrict__ Wh, const float* __restrict__ Wfp,
                            unsigned short* __restrict__ whT, unsigned short* __restrict__ wfpT) {
    int o = blockIdx.x * blockDim.x + threadIdx.x;
    if (o < RROUNDS * FDIM * FDIM) {
        int r = o >> 12, rem = o & 4095, j = rem >> 6, k = rem & 63;
        whT[o] = f2bf(Wh[r * 4096 + k * 64 + j]);
    } else {
        int o2 = o - RROUNDS * FDIM * FDIM;
        int r = o2 >> 13, rem = o2 & 8191, l = rem >> 6, k = rem & 63;
        wfpT[o2] = f2bf(Wfp[r * 8192 + k * 128 + l]);
    }
}

__global__ void init_kernel(const int* __restrict__ feat, const float* __restrict__ table,
                            unsigned short* __restrict__ emb, float* __restrict__ f, int n) {
    int gid = blockIdx.x * blockDim.x + threadIdx.x;
    if (gid < n * FDIM) {
        int node = gid >> 6;
        int d = gid & 63;
        emb[gid] = f2bf(table[feat[node] * FDIM + d]);
    }
    if (gid < LFP) f[gid] = 0.f;
}

// one wave per node: v[n] = emb[n] + sum_{nbr} emb[nbr], via CSR.
// 8 neighbors/iter x 8 lanes x bf16x8(16B) = one full 128B emb row per neighbor.
// No LDS, no atomics -> 8 waves/SIMD occupancy; reduction via shfl_xor only.
__global__ __launch_bounds__(256) void gather_kernel(
        const unsigned short* __restrict__ emb, const int* __restrict__ rp,
        const int* __restrict__ csr, unsigned short* __restrict__ vbuf, int N) {
    int wid = (int)((blockIdx.x * 256 + threadIdx.x) >> 6);
    int lane = threadIdx.x & 63;
    if (wid >= N) return;
    int start = rp[wid], end = rp[wid + 1];
    int grp = lane >> 3, q = lane & 7;
    float acc[8] = {0.f, 0.f, 0.f, 0.f, 0.f, 0.f, 0.f, 0.f};
    for (int j = start + grp; j < end; j += 8) {
        int nb = csr[j];
        bf16x8 u = *reinterpret_cast<const bf16x8*>(emb + (size_t)nb * 64 + q * 8);
#pragma unroll
        for (int x = 0; x < 8; ++x) acc[x] += bf2f((unsigned short)u[x]);
    }
#pragma unroll
    for (int x = 0; x < 8; ++x) {
        acc[x] += __shfl_xor(acc[x], 8);
        acc[x] += __shfl_xor(acc[x], 16);
        acc[x] += __shfl_xor(acc[x], 32);
    }
    if (grp == 0) {
        bf16x8 self = *reinterpret_cast<const bf16x8*>(emb + (size_t)wid * 64 + q * 8);
        bf16x8 o;
#pragma unroll
        for (int x = 0; x < 8; ++x) o[x] = (short)f2bf(acc[x] + bf2f((unsigned short)self[x]));
        *reinterpret_cast<bf16x8*>(vbuf + (size_t)wid * 64 + q * 8) = o;
    }
}

// MFMA MLP (round-3 known-good): block = 64 nodes, 4 waves. LDS rows padded to
// 72 bf16 (144B = 9x16B): aligned b128 access, conflict-free.
__global__ __launch_bounds__(256) void mlp_kernel(
        const unsigned short* __restrict__ vbuf, unsigned short* __restrict__ emb_out,
        const unsigned short* __restrict__ whT, const unsigned short* __restrict__ wfpT,
        const float* __restrict__ bh, const float* __restrict__ bfp,
        float* __restrict__ f, int N) {
    __shared__ unsigned short sV[BM * 72];
    __shared__ unsigned short sWh[64 * 72];
    __shared__ unsigned short sWfp[128 * 72];
    __shared__ float sBh[64];
    __shared__ float sBfp[128];
    __shared__ float sF[128];

    int tid = threadIdx.x;
    int base = blockIdx.x * BM;

    if (tid < 128) { sF[tid] = 0.f; sBfp[tid] = bfp[tid]; }
    if (tid < 64) sBh[tid] = bh[tid];

#pragma unroll
    for (int it = 0; it < 2; ++it) {  // WhT: 4096 bf16
        int idx = it * 2048 + tid * 8;
        *reinterpret_cast<bf16x8*>(sWh + (idx >> 6) * 72 + (idx & 63)) =
            *reinterpret_cast<const bf16x8*>(whT + idx);
    }
#pragma unroll
    for (int it = 0; it < 4; ++it) {  // WfpT: 8192 bf16
        int idx = it * 2048 + tid * 8;
        *reinterpret_cast<bf16x8*>(sWfp + (idx >> 6) * 72 + (idx & 63)) =
            *reinterpret_cast<const bf16x8*>(wfpT + idx);
    }
#pragma unroll
    for (int it = 0; it < 2; ++it) {  // V tile
        int idx = it * 2048 + tid * 8;
        int nl = idx >> 6, k0 = idx & 63;
        bf16x8 vv;
        if (base + nl < N) {
            vv = *reinterpret_cast<const bf16x8*>(vbuf + (size_t)base * 64 + idx);
        } else {
#pragma unroll
            for (int j = 0; j < 8; ++j) vv[j] = 0;
        }
        *reinterpret_cast<bf16x8*>(sV + nl * 72 + k0) = vv;
    }
    __syncthreads();

    int lane = tid & 63, w = tid >> 6;
    int m16 = lane & 15, g = lane >> 4;
    int arow = w * 16 + m16;

    // ---- GEMM1: r = relu(V @ Wh + bh), per wave a 16x64 strip ----
    bf16x8 a0 = *reinterpret_cast<const bf16x8*>(sV + arow * 72 + g * 8);
    bf16x8 a1 = *reinterpret_cast<const bf16x8*>(sV + arow * 72 + 32 + g * 8);
    f32x4 acc[4];
#pragma unroll
    for (int c = 0; c < 4; ++c) {
        bf16x8 b0 = *reinterpret_cast<const bf16x8*>(sWh + (c * 16 + m16) * 72 + g * 8);
        bf16x8 b1 = *reinterpret_cast<const bf16x8*>(sWh + (c * 16 + m16) * 72 + 32 + g * 8);
        f32x4 z = {0.f, 0.f, 0.f, 0.f};
        z = __builtin_amdgcn_mfma_f32_16x16x32_bf16(a0, b0, z, 0, 0, 0);
        z = __builtin_amdgcn_mfma_f32_16x16x32_bf16(a1, b1, z, 0, 0, 0);
        acc[c] = z;
    }
    __syncthreads();  // all reads of sV done before rewrite
    // C layout: row=(lane>>4)*4+reg, col=c*16+(lane&15)
#pragma unroll
    for (int c = 0; c < 4; ++c) {
        float bias = sBh[c * 16 + m16];
#pragma unroll
        for (int reg = 0; reg < 4; ++reg) {
            float rv = fmaxf(acc[c][reg] + bias, 0.f);
            sV[(w * 16 + g * 4 + reg) * 72 + c * 16 + m16] = f2bf(rv);
        }
    }
    __syncthreads();

    // store r -> emb (next round)
#pragma unroll
    for (int it = 0; it < 2; ++it) {
        int idx = it * 2048 + tid * 8;
        int nl = idx >> 6;
        if (base + nl < N)
            *reinterpret_cast<bf16x8*>(emb_out + (size_t)base * 64 + idx) =
                *reinterpret_cast<const bf16x8*>(sV + nl * 72 + (idx & 63));
    }

    // ---- GEMM2: z = r @ Wfp + bfp  (16 x 128 per wave) ----
    bf16x8 ra0 = *reinterpret_cast<const bf16x8*>(sV + arow * 72 + g * 8);
    bf16x8 ra1 = *reinterpret_cast<const bf16x8*>(sV + arow * 72 + 32 + g * 8);
    f32x4 z[8];
#pragma unroll
    for (int t = 0; t < 8; ++t) {
        bf16x8 b0 = *reinterpret_cast<const bf16x8*>(sWfp + (t * 16 + m16) * 72 + g * 8);
        bf16x8 b1 = *reinterpret_cast<const bf16x8*>(sWfp + (t * 16 + m16) * 72 + 32 + g * 8);
        f32x4 zz = {0.f, 0.f, 0.f, 0.f};
        zz = __builtin_amdgcn_mfma_f32_16x16x32_bf16(ra0, b0, zz, 0, 0, 0);
        zz = __builtin_amdgcn_mfma_f32_16x16x32_bf16(ra1, b1, zz, 0, 0, 0);
        float bias = sBfp[t * 16 + m16];
#pragma unroll
        for (int reg = 0; reg < 4; ++reg) zz[reg] += bias;
        z[t] = zz;
    }

    // ---- softmax over 128 cols per node-row (rows live in 16-lane groups) ----
#pragma unroll
    for (int reg = 0; reg < 4; ++reg) {
        float mx = -1e30f;
#pragma unroll
        for (int t = 0; t < 8; ++t) mx = fmaxf(mx, z[t][reg]);
#pragma unroll
        for (int d = 1; d < 16; d <<= 1) mx = fmaxf(mx, __shfl_xor(mx, d));
        float s = 0.f;
#pragma unroll
        for (int t = 0; t < 8; ++t) {
            float p = __expf(z[t][reg] - mx);
            z[t][reg] = p;
            s += p;
        }
#pragma unroll
        for (int d = 1; d < 16; d <<= 1) s += __shfl_xor(s, d);
        int node = base + w * 16 + g * 4 + reg;
        float inv = (node < N) ? (1.f / s) : 0.f;
#pragma unroll
        for (int t = 0; t < 8; ++t) z[t][reg] *= inv;
    }
#pragma unroll
    for (int t = 0; t < 8; ++t) {
        float v = z[t][0] + z[t][1] + z[t][2] + z[t][3];
        v += __shfl_xor(v, 16);
        v += __shfl_xor(v, 32);
        if (g == 0) atomicAdd(&sF[t * 16 + m16], v);
    }
    __syncthreads();
    if (tid < 128) unsafeAtomicAdd(&f[tid], sF[tid]);
}

__global__ void final_kernel(const float* __restrict__ f, const float* __restrict__ Wcl,
                             const float* __restrict__ bcl, float* __restrict__ out) {
    __shared__ float logits[10];
    int c = threadIdx.x;
    if (c < 10) {
        float acc = bcl[c];
        for (int l = 0; l < LFP; l++) acc = fmaf(f[l], Wcl[l * 10 + c], acc);
        logits[c] = acc;
    }
    __syncthreads();
    if (c == 0) {
        float m = -1e30f;
        for (int i = 0; i < 10; i++) m = fmaxf(m, logits[i]);
        float e[10], s = 0.f;
        for (int i = 0; i < 10; i++) { e[i] = __expf(logits[i] - m); s += e[i]; }
        for (int i = 0; i < 10; i++) out[i] = e[i] / s;
    }
}

extern "C" void kernel_launch(void* const* d_in, const int* in_sizes, int n_in,
                              void* d_out, int out_size, void* d_ws, size_t ws_size,
                              hipStream_t stream) {
    const int* feat = (const int*)d_in[0];
    const int* esrc = (const int*)d_in[1];
    const int* edst = (const int*)d_in[2];
    const float* table = (const float*)d_in[3];
    const float* Wh = (const float*)d_in[4];
    const float* bh = (const float*)d_in[5];
    const float* Wfp = (const float*)d_in[6];
    const float* bfp = (const float*)d_in[7];
    const float* Wcl = (const float*)d_in[8];
    const float* bcl = (const float*)d_in[9];
    float* out = (float*)d_out;
    int N = in_sizes[0];
    int nE = in_sizes[1];

    char* ws = (char*)d_ws;
    size_t off = 0;
    auto alloc = [&](size_t bytes) { void* p = ws + off; off += (bytes + 63) & ~(size_t)63; return p; };
    unsigned short* embA = (unsigned short*)alloc((size_t)N * 64 * 2);
    unsigned short* vbuf = (unsigned short*)alloc((size_t)N * 64 * 2);
    float* f           = (float*)alloc(LFP * 4);
    unsigned short* whT  = (unsigned short*)alloc(RROUNDS * 64 * 64 * 2);
    unsigned short* wfpT = (unsigned short*)alloc(RROUNDS * 128 * 64 * 2);
    int* cnt    = (int*)alloc((size_t)N * 4);
    int* rp     = (int*)alloc(((size_t)N + 1) * 4);
    int* cursor = (int*)alloc((size_t)N * 4);
    int* bsum   = (int*)alloc(((size_t)(N + SCAN_B - 1) / SCAN_B) * 4);
    int* csr    = (int*)alloc((size_t)nE * 4);

    int nblk_scan = (N + SCAN_B - 1) / SCAN_B;

    // CSR build (rebuilt every call — deterministic, no cross-call state)
    hipMemsetAsync(cnt, 0, (size_t)N * 4, stream);
    hist_kernel<<<(nE + 255) / 256, 256, 0, stream>>>(edst, cnt, nE);
    scan1_kernel<<<nblk_scan, 256, 0, stream>>>(cnt, rp, bsum, N);
    scan2_kernel<<<1, 64, 0, stream>>>(bsum, nblk_scan);
    scan3_kernel<<<(N + 256) / 256, 256, 0, stream>>>(rp, bsum, cursor, N, nE);
    fill_kernel<<<(nE + 255) / 256, 256, 0, stream>>>(esrc, edst, cursor, csr, nE);

    prep_kernel<<<192, 256, 0, stream>>>(Wh, Wfp, whT, wfpT);
    init_kernel<<<(N * FDIM + 255) / 256, 256, 0, stream>>>(feat, table, embA, f, N);

    for (int r = 0; r < RROUNDS; ++r) {
        gather_kernel<<<(N * 64 + 255) / 256, 256, 0, stream>>>(embA, rp, csr, vbuf, N);
        mlp_kernel<<<(N + BM - 1) / BM, 256, 0, stream>>>(
            vbuf, embA, whT + (size_t)r * 4096, wfpT + (size_t)r * 8192,
            bh + (size_t)r * FDIM, bfp + (size_t)r * LFP, f, N);
    }

    final_kernel<<<1, 64, 0, stream>>>(f, Wcl, bcl, out);
}